// Round 1
// baseline (103.999 us; speedup 1.0000x reference)
//
#include <hip/hip_runtime.h>
#include <hip/hip_bf16.h>
#include <math.h>

// Problem constants (fixed by the reference harness)
#define HD      768          // hidden dim H
#define TLEN    512          // seq_len T
#define NCH     8            // NC chunks
#define NLBL    8921         // NL labels
#define NNOTE   4            // NN notes
#define NCT     4096         // NC*T rows of encoding
#define ROWK    1115         // full rows of reshaped-weights per chunk: (NL*T)/NCT = 1115.125 -> 1115
#define F4      192          // HD/4 float4 per row

// Workspace layout (floats):
//   Bp[8][16][768]  : encoding partial block-column-sums (chunk c, row-seg of 32, h)
//   Tp[8][20][768]  : label_weights partial row-range sums (chunk k, seg, h)
#define BP_SEGS 16
#define TP_SEGS 20
#define TP_OFF  (NCH * BP_SEGS * HD)   // 98304 floats

// ---------------------------------------------------------------------------
// Kernel A: all the heavy memory reduction.
//   blocks [0,128)   : encoding block sums.  b = c*16+seg, 32 rows each.
//   blocks [128,288) : label_weights row-range sums. bb = k*20+seg, 56 rows
//                      each (last seg of each k: 51 rows; 19*56+51 = 1115).
// 192 threads = 3 waves; thread t owns float4 column t (192*4 = 768 = H).
// Fully coalesced: each wave's load = 64 consecutive float4 = 1 KiB.
// ---------------------------------------------------------------------------
__global__ __launch_bounds__(192) void talc_reduce_kernel(
    const float* __restrict__ enc,
    const float* __restrict__ lw,
    float* __restrict__ ws) {
  const int t = threadIdx.x;          // 0..191
  const int b = blockIdx.x;
  float4* Bp = (float4*)ws;
  float4* Tp = (float4*)(ws + TP_OFF);

  if (b < NCH * BP_SEGS) {
    // encoding: chunk c, 32-row segment seg
    const int c = b >> 4;
    const int seg = b & 15;
    const float4* base = (const float4*)enc + (size_t)(c * TLEN + seg * 32) * F4 + t;
    float4 acc = make_float4(0.f, 0.f, 0.f, 0.f);
#pragma unroll 8
    for (int r = 0; r < 32; ++r) {
      float4 v = base[(size_t)r * F4];
      acc.x += v.x; acc.y += v.y; acc.z += v.z; acc.w += v.w;
    }
    Bp[(size_t)b * F4 + t] = acc;
  } else {
    // label_weights (reinterpreted as (8921, 768) row-major): chunk k, seg
    const int bb = b - NCH * BP_SEGS;     // 0..159
    const int k = bb / TP_SEGS;
    const int seg = bb % TP_SEGS;
    const int r0 = seg * 56;
    const int rn = (seg == TP_SEGS - 1) ? 51 : 56;
    const float4* base = (const float4*)lw + (size_t)(k * ROWK + r0) * F4 + t;
    float4 acc = make_float4(0.f, 0.f, 0.f, 0.f);
#pragma unroll 4
    for (int r = 0; r < rn; ++r) {
      float4 v = base[(size_t)r * F4];
      acc.x += v.x; acc.y += v.y; acc.z += v.z; acc.w += v.w;
    }
    Tp[(size_t)bb * F4 + t] = acc;
  }
}

// ---------------------------------------------------------------------------
// Kernel B: tiny finish. One thread per h (3 blocks x 256).
//   B[c]     = sum of 16 partials            (encoding 512-block column sums)
//   T[k]     = sum of 20 partials            (label_weights 1115-row sums)
//   R[m]     = lw_reshaped[1115*m, h], m=0..8 (single rows)
//   G[k]     = R[k]*Esuf[k] + (T[k]-R[k])*E + R[k+1]*Epre[k+1]
//   Mc[n][c] = softmax over notes of the mask (0.25 if all masked,
//              else 1/cnt for unmasked notes, 0 for masked)
//   out[n,h] = sigmoid( sum_c Mc[n][c] * G[c] )
// ---------------------------------------------------------------------------
__global__ __launch_bounds__(256) void talc_finish_kernel(
    const float* __restrict__ lw,
    const int* __restrict__ ids,
    const float* __restrict__ ws,
    float* __restrict__ out) {
  const int h = blockIdx.x * 256 + threadIdx.x;   // 0..767
  if (h >= HD) return;
  const float* Bp = ws;
  const float* Tp = ws + TP_OFF;

  // encoding 512-block column sums
  float B[NCH];
#pragma unroll
  for (int c = 0; c < NCH; ++c) {
    float s = 0.f;
#pragma unroll
    for (int g = 0; g < BP_SEGS; ++g) s += Bp[(size_t)(c * BP_SEGS + g) * HD + h];
    B[c] = s;
  }
  float Esuf[NCH + 1];
  Esuf[NCH] = 0.f;
#pragma unroll
  for (int c = NCH - 1; c >= 0; --c) Esuf[c] = Esuf[c + 1] + B[c];
  float Epre[NCH + 1];
  Epre[0] = 0.f;
#pragma unroll
  for (int c = 1; c <= NCH; ++c) Epre[c] = Epre[c - 1] + B[c - 1];
  const float E = Esuf[0];

  // label_weights 1115-row range sums
  float Tk[NCH];
#pragma unroll
  for (int k = 0; k < NCH; ++k) {
    float s = 0.f;
#pragma unroll
    for (int g = 0; g < TP_SEGS; ++g) s += Tp[(size_t)(k * TP_SEGS + g) * HD + h];
    Tk[k] = s;
  }

  // single boundary rows R[m] = lwR[1115*m, h]
  float R[NCH + 1];
#pragma unroll
  for (int m = 0; m <= NCH; ++m) R[m] = lw[(size_t)(m * ROWK) * HD + h];

  // G[k]: top partial row + full rows + bottom partial row of chunk k's
  // region in the raw (Nn, Nl, NcT) reshape of the softmax weights.
  float G[NCH];
#pragma unroll
  for (int k = 0; k < NCH; ++k) {
    G[k] = R[k] * Esuf[k] + (Tk[k] - R[k]) * E + R[k + 1] * Epre[k + 1];
  }

  // mask softmax table Mc[n][c] and final scores
  int id[NNOTE];
#pragma unroll
  for (int n = 0; n < NNOTE; ++n) id[n] = ids[n];

  float score[NNOTE] = {0.f, 0.f, 0.f, 0.f};
#pragma unroll
  for (int c = 0; c < NCH; ++c) {
    int cnt = 0;
#pragma unroll
    for (int n = 0; n < NNOTE; ++n) cnt += (id[n] + 1 <= c) ? 1 : 0;
    const float inv = (cnt > 0) ? (1.f / (float)cnt) : 0.f;
#pragma unroll
    for (int n = 0; n < NNOTE; ++n) {
      const float m = (cnt == 0) ? 0.25f : (((id[n] + 1) <= c) ? inv : 0.f);
      score[n] += m * G[c];
    }
  }
#pragma unroll
  for (int n = 0; n < NNOTE; ++n) {
    out[(size_t)n * HD + h] = 1.f / (1.f + expf(-score[n]));
  }
}

extern "C" void kernel_launch(void* const* d_in, const int* in_sizes, int n_in,
                              void* d_out, int out_size, void* d_ws, size_t ws_size,
                              hipStream_t stream) {
  const float* enc = (const float*)d_in[0];       // (4096, 768)
  // d_in[1] = label_queries — provably unused (softmax over notes is
  // shift-invariant; the score term cancels exactly).
  const float* lw  = (const float*)d_in[2];       // (768, 8921) buffer, read as (8921, 768)
  const int*   ids = (const int*)d_in[3];         // (4,) note_end_chunk_ids
  // d_in[4] = seq_len (scalar 512) — structure hard-coded.
  float* ws  = (float*)d_ws;                      // needs (98304 + 122880) floats ≈ 884 KB
  float* out = (float*)d_out;                     // (4, 768) fp32

  talc_reduce_kernel<<<NCH * BP_SEGS + NCH * TP_SEGS, 192, 0, stream>>>(enc, lw, ws);
  talc_finish_kernel<<<3, 256, 0, stream>>>(lw, ids, ws, out);
}

// Round 2
// 103.796 us; speedup vs baseline: 1.0019x; 1.0019x over previous
//
#include <hip/hip_runtime.h>
#include <hip/hip_bf16.h>
#include <math.h>

// Problem constants (fixed by the reference harness)
#define HD      768          // hidden dim H
#define TLEN    512          // seq_len T
#define NCH     8            // NC chunks
#define NLBL    8921         // NL labels
#define NNOTE   4            // NN notes
#define NCT     4096         // NC*T rows of encoding
#define ROWK    1115         // full rows of reshaped-weights per chunk
#define F4      192          // HD/4 float4 per row

// Kernel A partition: exactly 256 blocks = 1 per CU, byte-balanced.
//   enc:  64 blocks  (8 chunks x 8 segs), 64 rows each        (192 KB/block)
//   lw :  192 blocks (8 chunks x 24 segs), 23x48 + 1x11 rows  (<=144 KB/block)
#define ENC_BLOCKS      64
#define ENC_SEGS        8     // per chunk
#define ENC_ROWS        64    // rows per enc block
#define LW_SEGS_PER_K   24
#define LW_ROWS         48    // rows per lw seg (last seg of each k: 11)
#define LW_BLOCKS       (NCH * LW_SEGS_PER_K)   // 192
#define NPART           (ENC_BLOCKS + LW_BLOCKS) // 256 partial rows of 768 floats

// ---------------------------------------------------------------------------
// Kernel A: all the heavy memory traffic (40 MB). 192 threads = 3 waves;
// thread t owns float4 column t (192*4 = 768 = H). Fully coalesced.
// One block per CU; ~8 outstanding 1 KiB wave-loads for latency hiding.
// ---------------------------------------------------------------------------
__global__ __launch_bounds__(192) void talc_reduce_kernel(
    const float* __restrict__ enc,
    const float* __restrict__ lw,
    float* __restrict__ ws) {
  const int t = threadIdx.x;          // 0..191
  const int b = blockIdx.x;           // 0..255
  float4* P = (float4*)ws;            // P[256][192] float4

  const float4* base;
  int rn;
  if (b < ENC_BLOCKS) {
    const int c = b >> 3;             // chunk
    const int seg = b & 7;
    base = (const float4*)enc + (size_t)(c * TLEN + seg * ENC_ROWS) * F4 + t;
    rn = ENC_ROWS;
  } else {
    const int bb = b - ENC_BLOCKS;    // 0..191
    const int k = bb / LW_SEGS_PER_K;
    const int seg = bb % LW_SEGS_PER_K;
    base = (const float4*)lw + (size_t)(k * ROWK + seg * LW_ROWS) * F4 + t;
    rn = (seg == LW_SEGS_PER_K - 1) ? (ROWK - (LW_SEGS_PER_K - 1) * LW_ROWS)  // 11
                                    : LW_ROWS;
  }

  float4 acc = make_float4(0.f, 0.f, 0.f, 0.f);
#pragma unroll 8
  for (int r = 0; r < rn; ++r) {
    float4 v = base[(size_t)r * F4];
    acc.x += v.x; acc.y += v.y; acc.z += v.z; acc.w += v.w;
  }
  P[(size_t)b * F4 + t] = acc;
}

// ---------------------------------------------------------------------------
// Kernel B: finish. 6 blocks x 128 threads, one thread per h.
//   B[c]     = sum of 8 enc partials       (512-block column sums of encoding)
//   Tk[k]    = sum of 24 lw partials       (1115-row sums of reshaped weights)
//   R[m]     = lwR[1115*m, h], m=0..8      (boundary rows)
//   G[k]     = R[k]*Esuf[k] + (Tk[k]-R[k])*E + R[k+1]*Epre[k+1]
//   Mc[n][c] = softmax over notes of the chunk mask (0.25 if all masked,
//              else 1/cnt for unmasked, 0 for masked)
//   out[n,h] = sigmoid( sum_c Mc[n][c] * G[c] )
// ---------------------------------------------------------------------------
__global__ __launch_bounds__(128) void talc_finish_kernel(
    const float* __restrict__ lw,
    const int* __restrict__ ids,
    const float* __restrict__ ws,
    float* __restrict__ out) {
  const int h = blockIdx.x * 128 + threadIdx.x;   // 0..767
  if (h >= HD) return;
  const float* P = ws;

  // encoding 512-block column sums
  float B[NCH];
#pragma unroll
  for (int c = 0; c < NCH; ++c) {
    float s = 0.f;
#pragma unroll
    for (int g = 0; g < ENC_SEGS; ++g) s += P[(size_t)(c * ENC_SEGS + g) * HD + h];
    B[c] = s;
  }
  float Esuf[NCH + 1];
  Esuf[NCH] = 0.f;
#pragma unroll
  for (int c = NCH - 1; c >= 0; --c) Esuf[c] = Esuf[c + 1] + B[c];
  float Epre[NCH + 1];
  Epre[0] = 0.f;
#pragma unroll
  for (int c = 1; c <= NCH; ++c) Epre[c] = Epre[c - 1] + B[c - 1];
  const float E = Esuf[0];

  // label_weights 1115-row range sums
  float Tk[NCH];
#pragma unroll
  for (int k = 0; k < NCH; ++k) {
    float s = 0.f;
#pragma unroll
    for (int g = 0; g < LW_SEGS_PER_K; ++g)
      s += P[(size_t)(ENC_BLOCKS + k * LW_SEGS_PER_K + g) * HD + h];
    Tk[k] = s;
  }

  // single boundary rows R[m] = lwR[1115*m, h]
  float R[NCH + 1];
#pragma unroll
  for (int m = 0; m <= NCH; ++m) R[m] = lw[(size_t)(m * ROWK) * HD + h];

  // G[k]: top partial row + full rows + bottom partial row of chunk k's
  // region in the raw (Nn, Nl, NcT) reshape of the softmax weights.
  float G[NCH];
#pragma unroll
  for (int k = 0; k < NCH; ++k) {
    G[k] = R[k] * Esuf[k] + (Tk[k] - R[k]) * E + R[k + 1] * Epre[k + 1];
  }

  // mask softmax table Mc[n][c] and final scores
  int id[NNOTE];
#pragma unroll
  for (int n = 0; n < NNOTE; ++n) id[n] = ids[n];

  float score[NNOTE] = {0.f, 0.f, 0.f, 0.f};
#pragma unroll
  for (int c = 0; c < NCH; ++c) {
    int cnt = 0;
#pragma unroll
    for (int n = 0; n < NNOTE; ++n) cnt += (id[n] + 1 <= c) ? 1 : 0;
    const float inv = (cnt > 0) ? (1.f / (float)cnt) : 0.f;
#pragma unroll
    for (int n = 0; n < NNOTE; ++n) {
      const float m = (cnt == 0) ? 0.25f : (((id[n] + 1) <= c) ? inv : 0.f);
      score[n] += m * G[c];
    }
  }
#pragma unroll
  for (int n = 0; n < NNOTE; ++n) {
    out[(size_t)n * HD + h] = 1.f / (1.f + expf(-score[n]));
  }
}

extern "C" void kernel_launch(void* const* d_in, const int* in_sizes, int n_in,
                              void* d_out, int out_size, void* d_ws, size_t ws_size,
                              hipStream_t stream) {
  const float* enc = (const float*)d_in[0];       // (4096, 768)
  // d_in[1] = label_queries — provably unused (softmax over notes is
  // shift-invariant; the identical-across-notes score term cancels exactly).
  const float* lw  = (const float*)d_in[2];       // (768, 8921) buffer, read as (8921, 768)
  const int*   ids = (const int*)d_in[3];         // (4,) note_end_chunk_ids
  // d_in[4] = seq_len (scalar 512) — structure hard-coded.
  float* ws  = (float*)d_ws;                      // 256*768 floats = 786 KB used
  float* out = (float*)d_out;                     // (4, 768) fp32

  talc_reduce_kernel<<<NPART, 192, 0, stream>>>(enc, lw, ws);
  talc_finish_kernel<<<6, 128, 0, stream>>>(lw, ids, ws, out);
}